// Round 1
// 345.024 us; speedup vs baseline: 1.0667x; 1.0667x over previous
//
#include <hip/hip_runtime.h>
#include <hip/hip_bf16.h>

#define NA   65536
#define DIN  512
#define DOUT 512
#define NE   8
#define NS   64
#define CAP  1280   // per-system perm capacity (count ~ 1024 +- 32, 8 sigma safe)
#define BM   128
#define BN   128
#define BK   32
#define TPS  (CAP / BM)   // row tiles per system = 10

typedef __attribute__((ext_vector_type(8))) __bf16 bf16x8;
typedef __attribute__((ext_vector_type(4))) float floatx4;

__device__ __forceinline__ void async_load16(const void* g, void* l) {
  __builtin_amdgcn_global_load_lds(
      (__attribute__((address_space(1))) void*)(void*)g,
      (__attribute__((address_space(3))) void*)l,
      16, 0, 0);
}

__global__ void init_kernel(int* cursors) {
  int t = threadIdx.x;
  if (t < NS) cursors[t] = t * CAP;
}

// Bucket atoms by system. 64 blocks x 4 atoms/thread: only 64 global atomics
// per system total (vs 256 before) -> less LLC atomic serialization.
__global__ void scatter_kernel(const int* __restrict__ bidx,
                               int* __restrict__ cursors,
                               int* __restrict__ perm) {
  __shared__ int hist[NS];
  __shared__ int base[NS];
  int t = threadIdx.x;
  if (t < NS) hist[t] = 0;
  __syncthreads();
  int n0 = blockIdx.x * 1024;
  int mys[4], myrank[4];
#pragma unroll
  for (int i = 0; i < 4; i++) {
    mys[i] = bidx[n0 + i * 256 + t];
    myrank[i] = atomicAdd(&hist[mys[i]], 1);
  }
  __syncthreads();
  if (t < NS && hist[t] > 0) base[t] = atomicAdd(&cursors[t], hist[t]);
  __syncthreads();
#pragma unroll
  for (int i = 0; i < 4; i++)
    perm[base[mys[i]] + myrank[i]] = n0 + i * 256 + t;
}

// Gather+convert: xp[s*CAP + r] = bf16(x[perm[s*CAP + r]]), K-contiguous.
// One wave per row: 2 float4 reads + 1 uint4 write per lane, fully coalesced.
// Pad rows (r >= count) left uninitialized -- GEMM masks those output rows.
__global__ void gather_kernel(const float* __restrict__ x,
                              const int* __restrict__ perm,
                              const int* __restrict__ cursors,
                              ushort* __restrict__ xp) {
  int rg = blockIdx.x * 4 + (threadIdx.x >> 6);  // global padded row
  int lane = threadIdx.x & 63;
  int s = rg / CAP;
  int r = rg - s * CAP;
  if (r >= cursors[s] - s * CAP) return;  // wave-uniform exit
  int pr = perm[rg];
  const float4* src = (const float4*)(x + (size_t)pr * DIN);
  float4 a = src[2 * lane], b = src[2 * lane + 1];
  union { bf16x8 v; uint4 u; } cv;
  cv.v[0] = (__bf16)a.x; cv.v[1] = (__bf16)a.y;
  cv.v[2] = (__bf16)a.z; cv.v[3] = (__bf16)a.w;
  cv.v[4] = (__bf16)b.x; cv.v[5] = (__bf16)b.y;
  cv.v[6] = (__bf16)b.z; cv.v[7] = (__bf16)b.w;
  *(uint4*)(xp + (size_t)rg * DIN + lane * 8) = cv.u;
}

// mixedW[s][o][i] = sum_e coeff[s][e] * W[e][o][i], bf16 K-contiguous.
// Grid (128, 8): 1024 blocks (4/CU) vs previous 256 (1/CU). Each block caches
// a 2048-elem chunk of all 8 experts in registers, reuses across 8 systems.
__global__ void mixw_kernel(const float* __restrict__ W,
                            const float* __restrict__ coeff,
                            ushort* __restrict__ mixedW) {
  int t = threadIdx.x;
  int base = blockIdx.x * 2048 + t * 8;
  float w[NE][8];
#pragma unroll
  for (int e = 0; e < NE; e++) {
    const float4* p = (const float4*)(W + e * (DOUT * DIN) + base);
    float4 a = p[0], b = p[1];
    w[e][0] = a.x; w[e][1] = a.y; w[e][2] = a.z; w[e][3] = a.w;
    w[e][4] = b.x; w[e][5] = b.y; w[e][6] = b.z; w[e][7] = b.w;
  }
  int s0 = blockIdx.y * 8;
  for (int si = 0; si < 8; si++) {
    int s = s0 + si;
    float o[8] = {0, 0, 0, 0, 0, 0, 0, 0};
#pragma unroll
    for (int e = 0; e < NE; e++) {
      float c = coeff[s * NE + e];  // wave-uniform scalar load
#pragma unroll
      for (int j = 0; j < 8; j++) o[j] += c * w[e][j];
    }
    union { bf16x8 v; uint4 u; } cv;
#pragma unroll
    for (int j = 0; j < 8; j++) cv.v[j] = (__bf16)o[j];
    *(uint4*)(mixedW + (size_t)s * (DOUT * DIN) + base) = cv.u;
  }
}

// Grouped GEMM, m97 structure: both A and B staged bf16 via global_load_lds
// (width 16), 128x128 tile, BK=32, 4 waves (2x2), 4x4 of 16x16x32 MFMA each.
// No VALU in the staging path; A reads are linear (xp is pre-permuted).
__global__ __launch_bounds__(256) void gemm_kernel(
    const ushort* __restrict__ xp, const ushort* __restrict__ mixedW,
    const int* __restrict__ perm, const int* __restrict__ cursors,
    const float* __restrict__ bias, float* __restrict__ out) {
  int st = blockIdx.y;            // s * TPS + rowtile
  int s = st / TPS;
  int tt = st - s * TPS;
  int count = cursors[s] - s * CAP;
  int r0 = tt * BM;
  if (r0 >= count) return;        // dead tile
  int rows = min(BM, count - r0);
  int n0 = blockIdx.x * BN;

  __shared__ __align__(16) ushort Alds[BM * BK];  // 8KB, [row][k] bf16
  __shared__ __align__(16) ushort Blds[BN * BK];  // 8KB, [o][k]  bf16
  __shared__ int prow[BM];

  int tid = threadIdx.x;
  int lane = tid & 63;
  int wave = tid >> 6;

  if (tid < BM) prow[tid] = perm[s * CAP + r0 + min(tid, rows - 1)];

  // Staging map: per wave-load j, region = j*4+wave holds 16 rows of 64B.
  // Lane covers row = region*16 + lane/4, k-bytes (lane&3)*16.
  // LDS dest is WAVE-UNIFORM base (HW adds lane*16).
  const ushort* aptr[2];
  const ushort* bptr[2];
  ushort* al[2];
  ushort* bl[2];
#pragma unroll
  for (int j = 0; j < 2; j++) {
    int region = j * 4 + wave;
    int row = region * 16 + (lane >> 2);
    int kc = (lane & 3) * 8;
    aptr[j] = xp + (size_t)(s * CAP + r0 + row) * DIN + kc;
    bptr[j] = mixedW + (size_t)s * (DOUT * DIN) + (size_t)(n0 + row) * DIN + kc;
    al[j] = Alds + region * 512;
    bl[j] = Blds + region * 512;
  }

  floatx4 acc[4][4];
#pragma unroll
  for (int mt = 0; mt < 4; mt++)
#pragma unroll
    for (int nt = 0; nt < 4; nt++) acc[mt][nt] = {0.f, 0.f, 0.f, 0.f};

  int wm = wave >> 1, wn = wave & 1;
  int m15 = lane & 15, quad = lane >> 4;

  for (int kk = 0; kk < DIN; kk += BK) {
#pragma unroll
    for (int j = 0; j < 2; j++) {
      async_load16(aptr[j] + kk, al[j]);
      async_load16(bptr[j] + kk, bl[j]);
    }
    __syncthreads();   // drains vmcnt -> staged tile visible
    bf16x8 af[4], bfm[4];
#pragma unroll
    for (int i = 0; i < 4; i++) {
      af[i]  = *(const bf16x8*)(Alds + (wm * 64 + i * 16 + m15) * BK + quad * 8);
      bfm[i] = *(const bf16x8*)(Blds + (wn * 64 + i * 16 + m15) * BK + quad * 8);
    }
#pragma unroll
    for (int mt = 0; mt < 4; mt++)
#pragma unroll
      for (int nt = 0; nt < 4; nt++)
        acc[mt][nt] = __builtin_amdgcn_mfma_f32_16x16x32_bf16(
            af[mt], bfm[nt], acc[mt][nt], 0, 0, 0);
    __syncthreads();   // all reads done before next staging overwrites
  }

  // Epilogue: C/D layout col=lane&15 (o), row=quad*4+reg (x-row in tile)
  float bv[4];
#pragma unroll
  for (int nt = 0; nt < 4; nt++) bv[nt] = bias[n0 + wn * 64 + nt * 16 + m15];

#pragma unroll
  for (int mt = 0; mt < 4; mt++) {
    int rb = wm * 64 + mt * 16 + quad * 4;
    int pr[4];
#pragma unroll
    for (int r = 0; r < 4; r++) pr[r] = prow[rb + r];
#pragma unroll
    for (int nt = 0; nt < 4; nt++) {
      int col = n0 + wn * 64 + nt * 16 + m15;
#pragma unroll
      for (int r = 0; r < 4; r++) {
        if (rb + r < rows)
          out[(size_t)pr[r] * DOUT + col] = acc[mt][nt][r] + bv[nt];
      }
    }
  }
}

extern "C" void kernel_launch(void* const* d_in, const int* in_sizes, int n_in,
                              void* d_out, int out_size, void* d_ws,
                              size_t ws_size, hipStream_t stream) {
  const float* x     = (const float*)d_in[0];
  const float* coeff = (const float*)d_in[1];
  const int*   bidx  = (const int*)d_in[2];
  const float* W     = (const float*)d_in[3];
  const float* bias  = (const float*)d_in[4];
  float* out = (float*)d_out;

  char* ws = (char*)d_ws;
  int* cursors   = (int*)ws;                                  // 256 B used
  int* perm      = (int*)(ws + 1024);                         // 320 KB
  ushort* mixedW = (ushort*)(ws + 1024 + NS * CAP * 4);       // 33.5 MB
  ushort* xp     = (ushort*)(ws + 1024 + NS * CAP * 4 +
                             (size_t)NS * DOUT * DIN * 2);    // 84 MB

  hipLaunchKernelGGL(init_kernel, dim3(1), dim3(64), 0, stream, cursors);
  hipLaunchKernelGGL(scatter_kernel, dim3(NA / 1024), dim3(256), 0, stream,
                     bidx, cursors, perm);
  hipLaunchKernelGGL(gather_kernel, dim3(NS * CAP / 4), dim3(256), 0, stream,
                     x, perm, cursors, xp);
  hipLaunchKernelGGL(mixw_kernel, dim3(DOUT * DIN / 2048, 8), dim3(256), 0,
                     stream, W, coeff, mixedW);
  hipLaunchKernelGGL(gemm_kernel, dim3(DOUT / BN, NS * TPS), dim3(256), 0,
                     stream, xp, mixedW, perm, cursors, bias, out);
}